// Round 12
// baseline (890.601 us; speedup 1.0000x reference)
//
#include <hip/hip_runtime.h>

#define N_NODES 100000
#define N_EDGES 3200000
#define FIN 512
#define FH 16
#define FC 40
#define NB_N ((N_NODES + 255) / 256)   // 391

// Native clang vector types for __builtin_nontemporal_load/store.
typedef int ivec4 __attribute__((ext_vector_type(4)));

// ---- kZero: zero the degree array ----

__global__ __launch_bounds__(256) void kZero(int* __restrict__ deg) {
  int i = blockIdx.x * 256 + threadIdx.x;
  if (i < 100352) deg[i] = 0;
}

// ---- kDeg: degree histogram via global atomics, full occupancy ----
// 2048 blocks x 256: scattered L2 atomics over 100k counters, ~32 hits each.

__global__ __launch_bounds__(256) void kDeg(const int* __restrict__ dst,
                                            int* __restrict__ deg) {
  const ivec4* d4 = (const ivec4*)dst;
  for (int i = blockIdx.x * 256 + threadIdx.x; i < N_EDGES / 4;
       i += gridDim.x * 256) {
    ivec4 v = __builtin_nontemporal_load(d4 + i);  // read-once stream
    atomicAdd(&deg[v.x], 1);
    atomicAdd(&deg[v.y], 1);
    atomicAdd(&deg[v.z], 1);
    atomicAdd(&deg[v.w], 1);
  }
}

// ---- kScan1: block-local exclusive scan of deg -> off(partial), totals T, dinv ----

__global__ __launch_bounds__(256) void kScan1(const int* __restrict__ deg,
                                              int* __restrict__ off,
                                              int* __restrict__ T,
                                              float* __restrict__ dinv) {
  __shared__ int s[256];
  int t = threadIdx.x, b = blockIdx.x;
  int node = b * 256 + t;
  int v = (node < N_NODES) ? deg[node] : 0;
  s[t] = v;
  __syncthreads();
  for (int d = 1; d < 256; d <<= 1) {
    int x = (t >= d) ? s[t - d] : 0;
    __syncthreads();
    s[t] += x;
    __syncthreads();
  }
  if (node < N_NODES) {
    off[node] = s[t] - v;                    // block-local exclusive
    dinv[node] = rsqrtf((float)(v + 1));     // +1 self-loop
  }
  if (t == 255) T[b] = s[t];
}

// ---- kScan2: exclusive scan of block totals -> Base ----

__global__ __launch_bounds__(512) void kScan2(const int* __restrict__ T,
                                              int* __restrict__ Base,
                                              int* __restrict__ off) {
  __shared__ int s[512];
  int t = threadIdx.x;
  int v = (t < NB_N) ? T[t] : 0;
  s[t] = v;
  __syncthreads();
  for (int d = 1; d < 512; d <<= 1) {
    int x = (t >= d) ? s[t - d] : 0;
    __syncthreads();
    s[t] += x;
    __syncthreads();
  }
  if (t < NB_N) Base[t] = s[t] - v;
  if (t == 0) off[N_NODES] = N_EDGES;
}

// ---- kScan3: add Base -> absolute off; init cursor ----

__global__ __launch_bounds__(256) void kScan3(int* __restrict__ off,
                                              const int* __restrict__ Base,
                                              int* __restrict__ cursor) {
  int t = threadIdx.x, b = blockIdx.x;
  int node = b * 256 + t;
  if (node < N_NODES) {
    int o = off[node] + Base[b];
    off[node] = o;
    cursor[node] = o;
  }
}

// ---- kPlace: scatter edges directly into CSR via global atomic cursors ----
// Replaces stage+kB entirely: saves 12.8MB write + 25.6MB read + 12.8MB write
// and runs at full occupancy (2048 blocks).

__global__ __launch_bounds__(256) void kPlace(const int* __restrict__ ei,
                                              int* __restrict__ cursor,
                                              int* __restrict__ csr) {
  const ivec4* s4 = (const ivec4*)ei;
  const ivec4* d4 = (const ivec4*)(ei + N_EDGES);
  for (int i = blockIdx.x * 256 + threadIdx.x; i < N_EDGES / 4;
       i += gridDim.x * 256) {
    ivec4 sv = __builtin_nontemporal_load(s4 + i);
    ivec4 dv = __builtin_nontemporal_load(d4 + i);
    int slot;
    slot = atomicAdd(&cursor[dv.x], 1);
    __builtin_nontemporal_store(sv.x, csr + slot);
    slot = atomicAdd(&cursor[dv.y], 1);
    __builtin_nontemporal_store(sv.y, csr + slot);
    slot = atomicAdd(&cursor[dv.z], 1);
    __builtin_nontemporal_store(sv.z, csr + slot);
    slot = atomicAdd(&cursor[dv.w], 1);
    __builtin_nontemporal_store(sv.w, csr + slot);
  }
}

// ---------------- layer 1 GEMM: p1 = dinv * (x @ W1) ----------------
// (exact 556.6µs-verified baseline version)

__global__ __launch_bounds__(256) void k_gemm1(const float* __restrict__ x,
                                               const float* __restrict__ W1,
                                               const float* __restrict__ dinv,
                                               float* __restrict__ p1) {
  __shared__ float xs[256 * 36];
  const int t = threadIdx.x;
  const int row0 = blockIdx.x * 256;
  const int row = row0 + t;
  float acc[FH];
#pragma unroll
  for (int c = 0; c < FH; c++) acc[c] = 0.0f;

  for (int kc = 0; kc < FIN; kc += 32) {
    float4 ld[8];
#pragma unroll
    for (int i = 0; i < 8; i++) {
      int idx = t + 256 * i;
      int r = idx >> 3, c4 = idx & 7;
      int gr = row0 + r;
      ld[i] = (gr < N_NODES)
                  ? *(const float4*)(x + (size_t)gr * FIN + kc + c4 * 4)
                  : make_float4(0.f, 0.f, 0.f, 0.f);
    }
    __syncthreads();
#pragma unroll
    for (int i = 0; i < 8; i++) {
      int idx = t + 256 * i;
      int r = idx >> 3, c4 = idx & 7;
      *(float4*)(&xs[r * 36 + c4 * 4]) = ld[i];
    }
    __syncthreads();
    float4 xr[8];
#pragma unroll
    for (int q = 0; q < 8; q++) xr[q] = *(const float4*)(&xs[t * 36 + q * 4]);
    const float4* w4 = (const float4*)(W1 + (size_t)kc * FH);  // wave-uniform
#pragma unroll
    for (int k = 0; k < 32; k++) {
      float xv = ((const float*)xr)[k];
      float4 wa = w4[k * 4 + 0], wb = w4[k * 4 + 1];
      float4 wc = w4[k * 4 + 2], wd = w4[k * 4 + 3];
      acc[0] = fmaf(xv, wa.x, acc[0]);   acc[1] = fmaf(xv, wa.y, acc[1]);
      acc[2] = fmaf(xv, wa.z, acc[2]);   acc[3] = fmaf(xv, wa.w, acc[3]);
      acc[4] = fmaf(xv, wb.x, acc[4]);   acc[5] = fmaf(xv, wb.y, acc[5]);
      acc[6] = fmaf(xv, wb.z, acc[6]);   acc[7] = fmaf(xv, wb.w, acc[7]);
      acc[8] = fmaf(xv, wc.x, acc[8]);   acc[9] = fmaf(xv, wc.y, acc[9]);
      acc[10] = fmaf(xv, wc.z, acc[10]); acc[11] = fmaf(xv, wc.w, acc[11]);
      acc[12] = fmaf(xv, wd.x, acc[12]); acc[13] = fmaf(xv, wd.y, acc[13]);
      acc[14] = fmaf(xv, wd.z, acc[14]); acc[15] = fmaf(xv, wd.w, acc[15]);
    }
  }

  if (row < N_NODES) {
    float dv = dinv[row];
#pragma unroll
    for (int c = 0; c < FH; c++) acc[c] *= dv;
#pragma unroll
    for (int q = 0; q < 4; q++)
      *(float4*)(p1 + (size_t)row * FH + q * 4) = ((const float4*)acc)[q];
  }
}

// ---- gather layer 1: q = dinv * relu(dinv * (p1[self] + sum p1[src]) + b1) ----
// one wave per node; csr reads NT (read-once stream, keep L2 for p1 table).

__global__ __launch_bounds__(256) void k_gather1(const int* __restrict__ off,
                                                 const int* __restrict__ csr,
                                                 const float* __restrict__ p1,
                                                 const float* __restrict__ dinv,
                                                 const float* __restrict__ b1,
                                                 float* __restrict__ q) {
  int lane = threadIdx.x & 63;
  int node = blockIdx.x * 4 + (threadIdx.x >> 6);
  int start = off[node];
  int end = off[node + 1];
  int slot = lane >> 2, comp = lane & 3;
  float4 acc = make_float4(0.f, 0.f, 0.f, 0.f);
  if (slot == 0)  // self-loop
    acc = *(const float4*)(p1 + (size_t)node * FH + comp * 4);
  for (int base = start; base < end; base += 32) {
    int e0 = base + slot, e1 = e0 + 16;
    int s0 = (e0 < end) ? __builtin_nontemporal_load(csr + e0) : -1;
    int s1 = (e1 < end) ? __builtin_nontemporal_load(csr + e1) : -1;
    if (s0 >= 0) {
      float4 v = *(const float4*)(p1 + (size_t)s0 * FH + comp * 4);
      acc.x += v.x; acc.y += v.y; acc.z += v.z; acc.w += v.w;
    }
    if (s1 >= 0) {
      float4 v = *(const float4*)(p1 + (size_t)s1 * FH + comp * 4);
      acc.x += v.x; acc.y += v.y; acc.z += v.z; acc.w += v.w;
    }
  }
#pragma unroll
  for (int m = 4; m <= 32; m <<= 1) {
    acc.x += __shfl_xor(acc.x, m);
    acc.y += __shfl_xor(acc.y, m);
    acc.z += __shfl_xor(acc.z, m);
    acc.w += __shfl_xor(acc.w, m);
  }
  float dv = dinv[node];
  if (lane < 4) {  // comp == lane
    float4 bb = *(const float4*)(b1 + lane * 4);
    float4 r;
    r.x = fmaxf(fmaf(acc.x, dv, bb.x), 0.f) * dv;
    r.y = fmaxf(fmaf(acc.y, dv, bb.y), 0.f) * dv;
    r.z = fmaxf(fmaf(acc.z, dv, bb.z), 0.f) * dv;
    r.w = fmaxf(fmaf(acc.w, dv, bb.w), 0.f) * dv;
    *(float4*)(q + (size_t)node * FH + lane * 4) = r;
  }
}

// ---- gather layer 2 + W2 matvec + log_softmax, fused ----

__global__ __launch_bounds__(256) void k_gather2(const int* __restrict__ off,
                                                 const int* __restrict__ csr,
                                                 const float* __restrict__ q,
                                                 const float* __restrict__ dinv,
                                                 const float* __restrict__ W2,
                                                 const float* __restrict__ b2,
                                                 float* __restrict__ out) {
  int lane = threadIdx.x & 63;
  int node = blockIdx.x * 4 + (threadIdx.x >> 6);
  int start = off[node];
  int end = off[node + 1];
  int slot = lane >> 2, comp = lane & 3;
  float4 acc = make_float4(0.f, 0.f, 0.f, 0.f);
  if (slot == 0)  // self-loop
    acc = *(const float4*)(q + (size_t)node * FH + comp * 4);
  for (int base = start; base < end; base += 32) {
    int e0 = base + slot, e1 = e0 + 16;
    int s0 = (e0 < end) ? __builtin_nontemporal_load(csr + e0) : -1;
    int s1 = (e1 < end) ? __builtin_nontemporal_load(csr + e1) : -1;
    if (s0 >= 0) {
      float4 v = *(const float4*)(q + (size_t)s0 * FH + comp * 4);
      acc.x += v.x; acc.y += v.y; acc.z += v.z; acc.w += v.w;
    }
    if (s1 >= 0) {
      float4 v = *(const float4*)(q + (size_t)s1 * FH + comp * 4);
      acc.x += v.x; acc.y += v.y; acc.z += v.z; acc.w += v.w;
    }
  }
#pragma unroll
  for (int m = 4; m <= 32; m <<= 1) {
    acc.x += __shfl_xor(acc.x, m);
    acc.y += __shfl_xor(acc.y, m);
    acc.z += __shfl_xor(acc.z, m);
    acc.w += __shfl_xor(acc.w, m);
  }
  float dv = dinv[node];
  acc.x *= dv; acc.y *= dv; acc.z *= dv; acc.w *= dv;
  float t16[16];
  t16[comp * 4 + 0] = acc.x; t16[comp * 4 + 1] = acc.y;
  t16[comp * 4 + 2] = acc.z; t16[comp * 4 + 3] = acc.w;
#pragma unroll
  for (int m = 1; m <= 3; m++) {
    int oc = comp ^ m;
    t16[oc * 4 + 0] = __shfl_xor(acc.x, m);
    t16[oc * 4 + 1] = __shfl_xor(acc.y, m);
    t16[oc * 4 + 2] = __shfl_xor(acc.z, m);
    t16[oc * 4 + 3] = __shfl_xor(acc.w, m);
  }
  float z = -1e30f;
  if (lane < FC) {
    z = b2[lane];
#pragma unroll
    for (int k = 0; k < FH; k++) z = fmaf(t16[k], W2[k * FC + lane], z);
  }
  float mx = z;
#pragma unroll
  for (int d = 1; d < 64; d <<= 1) mx = fmaxf(mx, __shfl_xor(mx, d));
  float ex = (lane < FC) ? __expf(z - mx) : 0.f;
#pragma unroll
  for (int d = 1; d < 64; d <<= 1) ex += __shfl_xor(ex, d);
  float l = __logf(ex) + mx;
  if (lane < FC) out[(size_t)node * FC + lane] = z - l;
}

// ---------------- launch ----------------

extern "C" void kernel_launch(void* const* d_in, const int* in_sizes, int n_in,
                              void* d_out, int out_size, void* d_ws, size_t ws_size,
                              hipStream_t stream) {
  const float* x  = (const float*)d_in[0];
  const int*   ei = (const int*)d_in[1];  // [2, E] int32
  const float* W1 = (const float*)d_in[2];
  const float* b1 = (const float*)d_in[3];
  const float* W2 = (const float*)d_in[4];
  const float* b2 = (const float*)d_in[5];
  float* out = (float*)d_out;

  // workspace (ints): deg | off | cursor | T | Base | csr | dinv | p1 | q
  int* wsi    = (int*)d_ws;
  int* deg    = wsi;                    // 100352
  int* off    = deg + 100352;           // 100352 (off[N_NODES] used)
  int* cursor = off + 100352;           // 100352
  int* T      = cursor + 100352;        // 512
  int* Base   = T + 512;                // 512
  int* csr    = Base + 512;             // 3200000
  float* dinv = (float*)(csr + 3200000);    // 100352
  float* p1   = dinv + 100352;          // 1600000
  float* q    = p1 + 1600000;           // 1600000

  kZero  <<<392,  256, 0, stream>>>(deg);
  kDeg   <<<2048, 256, 0, stream>>>(ei + N_EDGES, deg);
  kScan1 <<<NB_N, 256, 0, stream>>>(deg, off, T, dinv);
  kScan2 <<<1,    512, 0, stream>>>(T, Base, off);
  kScan3 <<<NB_N, 256, 0, stream>>>(off, Base, cursor);
  kPlace <<<2048, 256, 0, stream>>>(ei, cursor, csr);
  k_gemm1  <<<NB_N, 256, 0, stream>>>(x, W1, dinv, p1);
  k_gather1<<<N_NODES / 4, 256, 0, stream>>>(off, csr, p1, dinv, b1, q);
  k_gather2<<<N_NODES / 4, 256, 0, stream>>>(off, csr, q, dinv, W2, b2, out);
}

// Round 13
// 850.992 us; speedup vs baseline: 1.0465x; 1.0465x over previous
//
#include <hip/hip_runtime.h>

#define N_NODES 100000
#define N_EDGES 3200000
#define FIN 512
#define FH 16
#define FC 40
#define NB_N ((N_NODES + 255) / 256)   // 391

// Native clang vector types for __builtin_nontemporal_load.
// NOTE (R12 lesson): NT *loads* on read-once streams are fine (FETCH_SIZE
// near-ideal). NT *stores* on scattered 4B singles cause ~16x write
// amplification (199MB for 12.8MB useful) — never NT-store partial lines.
typedef int ivec4 __attribute__((ext_vector_type(4)));

// ---- kZero: zero the degree array ----

__global__ __launch_bounds__(256) void kZero(int* __restrict__ deg) {
  int i = blockIdx.x * 256 + threadIdx.x;
  if (i < 100352) deg[i] = 0;
}

// ---- kDeg: degree histogram via global atomics, full occupancy ----

__global__ __launch_bounds__(256) void kDeg(const int* __restrict__ dst,
                                            int* __restrict__ deg) {
  const ivec4* d4 = (const ivec4*)dst;
  for (int i = blockIdx.x * 256 + threadIdx.x; i < N_EDGES / 4;
       i += gridDim.x * 256) {
    ivec4 v = __builtin_nontemporal_load(d4 + i);  // read-once stream
    atomicAdd(&deg[v.x], 1);
    atomicAdd(&deg[v.y], 1);
    atomicAdd(&deg[v.z], 1);
    atomicAdd(&deg[v.w], 1);
  }
}

// ---- kScan1: block-local exclusive scan of deg -> off(partial), totals T, dinv ----

__global__ __launch_bounds__(256) void kScan1(const int* __restrict__ deg,
                                              int* __restrict__ off,
                                              int* __restrict__ T,
                                              float* __restrict__ dinv) {
  __shared__ int s[256];
  int t = threadIdx.x, b = blockIdx.x;
  int node = b * 256 + t;
  int v = (node < N_NODES) ? deg[node] : 0;
  s[t] = v;
  __syncthreads();
  for (int d = 1; d < 256; d <<= 1) {
    int x = (t >= d) ? s[t - d] : 0;
    __syncthreads();
    s[t] += x;
    __syncthreads();
  }
  if (node < N_NODES) {
    off[node] = s[t] - v;                    // block-local exclusive
    dinv[node] = rsqrtf((float)(v + 1));     // +1 self-loop
  }
  if (t == 255) T[b] = s[t];
}

// ---- kScan2: exclusive scan of block totals -> Base ----

__global__ __launch_bounds__(512) void kScan2(const int* __restrict__ T,
                                              int* __restrict__ Base,
                                              int* __restrict__ off) {
  __shared__ int s[512];
  int t = threadIdx.x;
  int v = (t < NB_N) ? T[t] : 0;
  s[t] = v;
  __syncthreads();
  for (int d = 1; d < 512; d <<= 1) {
    int x = (t >= d) ? s[t - d] : 0;
    __syncthreads();
    s[t] += x;
    __syncthreads();
  }
  if (t < NB_N) Base[t] = s[t] - v;
  if (t == 0) off[N_NODES] = N_EDGES;
}

// ---- kScan3: add Base -> absolute off; init cursor ----

__global__ __launch_bounds__(256) void kScan3(int* __restrict__ off,
                                              const int* __restrict__ Base,
                                              int* __restrict__ cursor) {
  int t = threadIdx.x, b = blockIdx.x;
  int node = b * 256 + t;
  if (node < N_NODES) {
    int o = off[node] + Base[b];
    off[node] = o;
    cursor[node] = o;
  }
}

// ---- kPlace: scatter edges directly into CSR via global atomic cursors ----
// csr stores are REGULAR cached stores: the 12.8MB csr region is L2-resident,
// so scattered 4B stores coalesce in L2 (~1 writeback/line) instead of the
// NT-store 16x write amplification measured in R12 (199MB -> expect ~15-30MB).

__global__ __launch_bounds__(256) void kPlace(const int* __restrict__ ei,
                                              int* __restrict__ cursor,
                                              int* __restrict__ csr) {
  const ivec4* s4 = (const ivec4*)ei;
  const ivec4* d4 = (const ivec4*)(ei + N_EDGES);
  for (int i = blockIdx.x * 256 + threadIdx.x; i < N_EDGES / 4;
       i += gridDim.x * 256) {
    ivec4 sv = __builtin_nontemporal_load(s4 + i);
    ivec4 dv = __builtin_nontemporal_load(d4 + i);
    int slot;
    slot = atomicAdd(&cursor[dv.x], 1); csr[slot] = sv.x;
    slot = atomicAdd(&cursor[dv.y], 1); csr[slot] = sv.y;
    slot = atomicAdd(&cursor[dv.z], 1); csr[slot] = sv.z;
    slot = atomicAdd(&cursor[dv.w], 1); csr[slot] = sv.w;
  }
}

// ---------------- layer 1 GEMM: p1 = dinv * (x @ W1) ----------------
// (exact 556.6µs-verified baseline version)

__global__ __launch_bounds__(256) void k_gemm1(const float* __restrict__ x,
                                               const float* __restrict__ W1,
                                               const float* __restrict__ dinv,
                                               float* __restrict__ p1) {
  __shared__ float xs[256 * 36];
  const int t = threadIdx.x;
  const int row0 = blockIdx.x * 256;
  const int row = row0 + t;
  float acc[FH];
#pragma unroll
  for (int c = 0; c < FH; c++) acc[c] = 0.0f;

  for (int kc = 0; kc < FIN; kc += 32) {
    float4 ld[8];
#pragma unroll
    for (int i = 0; i < 8; i++) {
      int idx = t + 256 * i;
      int r = idx >> 3, c4 = idx & 7;
      int gr = row0 + r;
      ld[i] = (gr < N_NODES)
                  ? *(const float4*)(x + (size_t)gr * FIN + kc + c4 * 4)
                  : make_float4(0.f, 0.f, 0.f, 0.f);
    }
    __syncthreads();
#pragma unroll
    for (int i = 0; i < 8; i++) {
      int idx = t + 256 * i;
      int r = idx >> 3, c4 = idx & 7;
      *(float4*)(&xs[r * 36 + c4 * 4]) = ld[i];
    }
    __syncthreads();
    float4 xr[8];
#pragma unroll
    for (int q = 0; q < 8; q++) xr[q] = *(const float4*)(&xs[t * 36 + q * 4]);
    const float4* w4 = (const float4*)(W1 + (size_t)kc * FH);  // wave-uniform
#pragma unroll
    for (int k = 0; k < 32; k++) {
      float xv = ((const float*)xr)[k];
      float4 wa = w4[k * 4 + 0], wb = w4[k * 4 + 1];
      float4 wc = w4[k * 4 + 2], wd = w4[k * 4 + 3];
      acc[0] = fmaf(xv, wa.x, acc[0]);   acc[1] = fmaf(xv, wa.y, acc[1]);
      acc[2] = fmaf(xv, wa.z, acc[2]);   acc[3] = fmaf(xv, wa.w, acc[3]);
      acc[4] = fmaf(xv, wb.x, acc[4]);   acc[5] = fmaf(xv, wb.y, acc[5]);
      acc[6] = fmaf(xv, wb.z, acc[6]);   acc[7] = fmaf(xv, wb.w, acc[7]);
      acc[8] = fmaf(xv, wc.x, acc[8]);   acc[9] = fmaf(xv, wc.y, acc[9]);
      acc[10] = fmaf(xv, wc.z, acc[10]); acc[11] = fmaf(xv, wc.w, acc[11]);
      acc[12] = fmaf(xv, wd.x, acc[12]); acc[13] = fmaf(xv, wd.y, acc[13]);
      acc[14] = fmaf(xv, wd.z, acc[14]); acc[15] = fmaf(xv, wd.w, acc[15]);
    }
  }

  if (row < N_NODES) {
    float dv = dinv[row];
#pragma unroll
    for (int c = 0; c < FH; c++) acc[c] *= dv;
#pragma unroll
    for (int q = 0; q < 4; q++)
      *(float4*)(p1 + (size_t)row * FH + q * 4) = ((const float4*)acc)[q];
  }
}

// ---- gather layer 1: q = dinv * relu(dinv * (p1[self] + sum p1[src]) + b1) ----

__global__ __launch_bounds__(256) void k_gather1(const int* __restrict__ off,
                                                 const int* __restrict__ csr,
                                                 const float* __restrict__ p1,
                                                 const float* __restrict__ dinv,
                                                 const float* __restrict__ b1,
                                                 float* __restrict__ q) {
  int lane = threadIdx.x & 63;
  int node = blockIdx.x * 4 + (threadIdx.x >> 6);
  int start = off[node];
  int end = off[node + 1];
  int slot = lane >> 2, comp = lane & 3;
  float4 acc = make_float4(0.f, 0.f, 0.f, 0.f);
  if (slot == 0)  // self-loop
    acc = *(const float4*)(p1 + (size_t)node * FH + comp * 4);
  for (int base = start; base < end; base += 32) {
    int e0 = base + slot, e1 = e0 + 16;
    int s0 = (e0 < end) ? __builtin_nontemporal_load(csr + e0) : -1;
    int s1 = (e1 < end) ? __builtin_nontemporal_load(csr + e1) : -1;
    if (s0 >= 0) {
      float4 v = *(const float4*)(p1 + (size_t)s0 * FH + comp * 4);
      acc.x += v.x; acc.y += v.y; acc.z += v.z; acc.w += v.w;
    }
    if (s1 >= 0) {
      float4 v = *(const float4*)(p1 + (size_t)s1 * FH + comp * 4);
      acc.x += v.x; acc.y += v.y; acc.z += v.z; acc.w += v.w;
    }
  }
#pragma unroll
  for (int m = 4; m <= 32; m <<= 1) {
    acc.x += __shfl_xor(acc.x, m);
    acc.y += __shfl_xor(acc.y, m);
    acc.z += __shfl_xor(acc.z, m);
    acc.w += __shfl_xor(acc.w, m);
  }
  float dv = dinv[node];
  if (lane < 4) {  // comp == lane
    float4 bb = *(const float4*)(b1 + lane * 4);
    float4 r;
    r.x = fmaxf(fmaf(acc.x, dv, bb.x), 0.f) * dv;
    r.y = fmaxf(fmaf(acc.y, dv, bb.y), 0.f) * dv;
    r.z = fmaxf(fmaf(acc.z, dv, bb.z), 0.f) * dv;
    r.w = fmaxf(fmaf(acc.w, dv, bb.w), 0.f) * dv;
    *(float4*)(q + (size_t)node * FH + lane * 4) = r;
  }
}

// ---- gather layer 2 + W2 matvec + log_softmax, fused ----

__global__ __launch_bounds__(256) void k_gather2(const int* __restrict__ off,
                                                 const int* __restrict__ csr,
                                                 const float* __restrict__ q,
                                                 const float* __restrict__ dinv,
                                                 const float* __restrict__ W2,
                                                 const float* __restrict__ b2,
                                                 float* __restrict__ out) {
  int lane = threadIdx.x & 63;
  int node = blockIdx.x * 4 + (threadIdx.x >> 6);
  int start = off[node];
  int end = off[node + 1];
  int slot = lane >> 2, comp = lane & 3;
  float4 acc = make_float4(0.f, 0.f, 0.f, 0.f);
  if (slot == 0)  // self-loop
    acc = *(const float4*)(q + (size_t)node * FH + comp * 4);
  for (int base = start; base < end; base += 32) {
    int e0 = base + slot, e1 = e0 + 16;
    int s0 = (e0 < end) ? __builtin_nontemporal_load(csr + e0) : -1;
    int s1 = (e1 < end) ? __builtin_nontemporal_load(csr + e1) : -1;
    if (s0 >= 0) {
      float4 v = *(const float4*)(q + (size_t)s0 * FH + comp * 4);
      acc.x += v.x; acc.y += v.y; acc.z += v.z; acc.w += v.w;
    }
    if (s1 >= 0) {
      float4 v = *(const float4*)(q + (size_t)s1 * FH + comp * 4);
      acc.x += v.x; acc.y += v.y; acc.z += v.z; acc.w += v.w;
    }
  }
#pragma unroll
  for (int m = 4; m <= 32; m <<= 1) {
    acc.x += __shfl_xor(acc.x, m);
    acc.y += __shfl_xor(acc.y, m);
    acc.z += __shfl_xor(acc.z, m);
    acc.w += __shfl_xor(acc.w, m);
  }
  float dv = dinv[node];
  acc.x *= dv; acc.y *= dv; acc.z *= dv; acc.w *= dv;
  float t16[16];
  t16[comp * 4 + 0] = acc.x; t16[comp * 4 + 1] = acc.y;
  t16[comp * 4 + 2] = acc.z; t16[comp * 4 + 3] = acc.w;
#pragma unroll
  for (int m = 1; m <= 3; m++) {
    int oc = comp ^ m;
    t16[oc * 4 + 0] = __shfl_xor(acc.x, m);
    t16[oc * 4 + 1] = __shfl_xor(acc.y, m);
    t16[oc * 4 + 2] = __shfl_xor(acc.z, m);
    t16[oc * 4 + 3] = __shfl_xor(acc.w, m);
  }
  float z = -1e30f;
  if (lane < FC) {
    z = b2[lane];
#pragma unroll
    for (int k = 0; k < FH; k++) z = fmaf(t16[k], W2[k * FC + lane], z);
  }
  float mx = z;
#pragma unroll
  for (int d = 1; d < 64; d <<= 1) mx = fmaxf(mx, __shfl_xor(mx, d));
  float ex = (lane < FC) ? __expf(z - mx) : 0.f;
#pragma unroll
  for (int d = 1; d < 64; d <<= 1) ex += __shfl_xor(ex, d);
  float l = __logf(ex) + mx;
  if (lane < FC) out[(size_t)node * FC + lane] = z - l;
}

// ---------------- launch ----------------

extern "C" void kernel_launch(void* const* d_in, const int* in_sizes, int n_in,
                              void* d_out, int out_size, void* d_ws, size_t ws_size,
                              hipStream_t stream) {
  const float* x  = (const float*)d_in[0];
  const int*   ei = (const int*)d_in[1];  // [2, E] int32
  const float* W1 = (const float*)d_in[2];
  const float* b1 = (const float*)d_in[3];
  const float* W2 = (const float*)d_in[4];
  const float* b2 = (const float*)d_in[5];
  float* out = (float*)d_out;

  // workspace (ints): deg | off | cursor | T | Base | csr | dinv | p1 | q
  int* wsi    = (int*)d_ws;
  int* deg    = wsi;                    // 100352
  int* off    = deg + 100352;           // 100352 (off[N_NODES] used)
  int* cursor = off + 100352;           // 100352
  int* T      = cursor + 100352;        // 512
  int* Base   = T + 512;                // 512
  int* csr    = Base + 512;             // 3200000
  float* dinv = (float*)(csr + 3200000);    // 100352
  float* p1   = dinv + 100352;          // 1600000
  float* q    = p1 + 1600000;           // 1600000

  kZero  <<<392,  256, 0, stream>>>(deg);
  kDeg   <<<2048, 256, 0, stream>>>(ei + N_EDGES, deg);
  kScan1 <<<NB_N, 256, 0, stream>>>(deg, off, T, dinv);
  kScan2 <<<1,    512, 0, stream>>>(T, Base, off);
  kScan3 <<<NB_N, 256, 0, stream>>>(off, Base, cursor);
  kPlace <<<2048, 256, 0, stream>>>(ei, cursor, csr);
  k_gemm1  <<<NB_N, 256, 0, stream>>>(x, W1, dinv, p1);
  k_gather1<<<N_NODES / 4, 256, 0, stream>>>(off, csr, p1, dinv, b1, q);
  k_gather2<<<N_NODES / 4, 256, 0, stream>>>(off, csr, q, dinv, W2, b2, out);
}

// Round 14
// 564.610 us; speedup vs baseline: 1.5774x; 1.5072x over previous
//
#include <hip/hip_runtime.h>

#define N_NODES 100000
#define N_EDGES 3200000
#define FIN 512
#define FH 16
#define FC 40
#define NB_N ((N_NODES + 255) / 256)   // 391
#define NBKT 391                        // dst buckets: dst>>8, 256 nodes each
#define NBLK_P 256                      // partition blocks
#define CHUNK (N_EDGES / NBLK_P)        // 12500 exactly

// R12/R13 lessons: NT *loads* on read-once streams are safe (FETCH_SIZE
// near-ideal). Scattered stores MUST be bucket-grouped for write locality —
// cross-XCD random scatter costs ~1 full-line writeback per 4B store
// (196MB for 12.8MB useful) whether cached or NT.
typedef int ivec4 __attribute__((ext_vector_type(4)));

// ---- kA1: per-block bucket histogram (no global atomics) ----

__global__ __launch_bounds__(256) void kA1(const int* __restrict__ dst,
                                           int* __restrict__ H) {
  __shared__ int h[NBKT];
  int t = threadIdx.x;
  for (int i = t; i < NBKT; i += 256) h[i] = 0;
  __syncthreads();
  const ivec4* d4 = (const ivec4*)(dst + blockIdx.x * CHUNK);
  for (int i = t; i < CHUNK / 4; i += 256) {
    ivec4 v = __builtin_nontemporal_load(d4 + i);  // read-once stream
    atomicAdd(&h[v.x >> 8], 1);
    atomicAdd(&h[v.y >> 8], 1);
    atomicAdd(&h[v.z >> 8], 1);
    atomicAdd(&h[v.w >> 8], 1);
  }
  __syncthreads();
  for (int i = t; i < NBKT; i += 256) H[blockIdx.x * NBKT + i] = h[i];
}

// ---- kA2: per-bucket column exclusive scan over blocks; totals T ----

__global__ __launch_bounds__(256) void kA2(const int* __restrict__ H,
                                           int* __restrict__ P,
                                           int* __restrict__ T) {
  __shared__ int s[256];
  int t = threadIdx.x, b = blockIdx.x;
  int v = H[t * NBKT + b];
  s[t] = v;
  __syncthreads();
  for (int d = 1; d < 256; d <<= 1) {
    int x = (t >= d) ? s[t - d] : 0;
    __syncthreads();
    s[t] += x;
    __syncthreads();
  }
  P[t * NBKT + b] = s[t] - v;  // exclusive sum of blocks < t for bucket b
  if (t == 255) T[b] = s[t];
}

// ---- kA3s: exclusive scan of bucket totals -> Base ----

__global__ __launch_bounds__(512) void kA3s(const int* __restrict__ T,
                                            int* __restrict__ Base,
                                            int* __restrict__ off) {
  __shared__ int s[512];
  int t = threadIdx.x;
  int v = (t < NBKT) ? T[t] : 0;
  s[t] = v;
  __syncthreads();
  for (int d = 1; d < 512; d <<= 1) {
    int x = (t >= d) ? s[t - d] : 0;
    __syncthreads();
    s[t] += x;
    __syncthreads();
  }
  if (t < NBKT) Base[t] = s[t] - v;
  if (t == 0) off[N_NODES] = N_EDGES;
}

// ---- kA3: place edges into bucket-grouped staging (LDS cursors) ----
// Per-block per-bucket cursor ranges -> stores advance CONTIGUOUSLY within
// each bucket (write-local, full-line coalescing). Cached stores.

__global__ __launch_bounds__(256) void kA3(const int* __restrict__ ei,
                                           const int* __restrict__ Base,
                                           const int* __restrict__ P,
                                           int* __restrict__ stage) {
  __shared__ int cur[NBKT];
  int t = threadIdx.x, blk = blockIdx.x;
  for (int i = t; i < NBKT; i += 256) cur[i] = Base[i] + P[blk * NBKT + i];
  __syncthreads();
  int base = blk * CHUNK;
  const ivec4* s4 = (const ivec4*)(ei + base);
  const ivec4* d4 = (const ivec4*)(ei + N_EDGES + base);
  for (int i = t; i < CHUNK / 4; i += 256) {
    ivec4 sv = __builtin_nontemporal_load(s4 + i);
    ivec4 dv = __builtin_nontemporal_load(d4 + i);
    int slot;
    slot = atomicAdd(&cur[dv.x >> 8], 1); stage[slot] = sv.x | ((dv.x & 255) << 17);
    slot = atomicAdd(&cur[dv.y >> 8], 1); stage[slot] = sv.y | ((dv.y & 255) << 17);
    slot = atomicAdd(&cur[dv.z >> 8], 1); stage[slot] = sv.z | ((dv.z & 255) << 17);
    slot = atomicAdd(&cur[dv.w >> 8], 1); stage[slot] = sv.w | ((dv.w & 255) << 17);
  }
}

// ---- kB: per-bucket CSR finalize: off[], dinv[], csr[] (all block-local) ----

__global__ __launch_bounds__(256) void kB(const int* __restrict__ stage,
                                          const int* __restrict__ Base,
                                          const int* __restrict__ T,
                                          int* __restrict__ off,
                                          int* __restrict__ csr,
                                          float* __restrict__ dinv) {
  __shared__ int hist[256], cursor[256], sc[256];
  int t = threadIdx.x, b = blockIdx.x;
  int base = Base[b], cnt = T[b];
  hist[t] = 0;
  __syncthreads();
  for (int i = t; i < cnt; i += 256) atomicAdd(&hist[stage[base + i] >> 17], 1);
  __syncthreads();
  int c = hist[t];
  sc[t] = c;
  __syncthreads();
  for (int d = 1; d < 256; d <<= 1) {
    int x = (t >= d) ? sc[t - d] : 0;
    __syncthreads();
    sc[t] += x;
    __syncthreads();
  }
  int excl = sc[t] - c;
  int node = b * 256 + t;
  if (node < N_NODES) {
    off[node] = base + excl;
    dinv[node] = rsqrtf((float)(c + 1));  // +1 self-loop
  }
  cursor[t] = excl;
  __syncthreads();
  for (int i = t; i < cnt; i += 256) {
    int pk = stage[base + i];
    int slot = atomicAdd(&cursor[pk >> 17], 1);  // LDS atomic
    csr[base + slot] = pk & 0x1FFFF;
  }
}

// ---------------- layer 1 GEMM: p1 = dinv * (x @ W1) ----------------
// (exact 556.6µs-verified baseline version)

__global__ __launch_bounds__(256) void k_gemm1(const float* __restrict__ x,
                                               const float* __restrict__ W1,
                                               const float* __restrict__ dinv,
                                               float* __restrict__ p1) {
  __shared__ float xs[256 * 36];
  const int t = threadIdx.x;
  const int row0 = blockIdx.x * 256;
  const int row = row0 + t;
  float acc[FH];
#pragma unroll
  for (int c = 0; c < FH; c++) acc[c] = 0.0f;

  for (int kc = 0; kc < FIN; kc += 32) {
    float4 ld[8];
#pragma unroll
    for (int i = 0; i < 8; i++) {
      int idx = t + 256 * i;
      int r = idx >> 3, c4 = idx & 7;
      int gr = row0 + r;
      ld[i] = (gr < N_NODES)
                  ? *(const float4*)(x + (size_t)gr * FIN + kc + c4 * 4)
                  : make_float4(0.f, 0.f, 0.f, 0.f);
    }
    __syncthreads();
#pragma unroll
    for (int i = 0; i < 8; i++) {
      int idx = t + 256 * i;
      int r = idx >> 3, c4 = idx & 7;
      *(float4*)(&xs[r * 36 + c4 * 4]) = ld[i];
    }
    __syncthreads();
    float4 xr[8];
#pragma unroll
    for (int q = 0; q < 8; q++) xr[q] = *(const float4*)(&xs[t * 36 + q * 4]);
    const float4* w4 = (const float4*)(W1 + (size_t)kc * FH);  // wave-uniform
#pragma unroll
    for (int k = 0; k < 32; k++) {
      float xv = ((const float*)xr)[k];
      float4 wa = w4[k * 4 + 0], wb = w4[k * 4 + 1];
      float4 wc = w4[k * 4 + 2], wd = w4[k * 4 + 3];
      acc[0] = fmaf(xv, wa.x, acc[0]);   acc[1] = fmaf(xv, wa.y, acc[1]);
      acc[2] = fmaf(xv, wa.z, acc[2]);   acc[3] = fmaf(xv, wa.w, acc[3]);
      acc[4] = fmaf(xv, wb.x, acc[4]);   acc[5] = fmaf(xv, wb.y, acc[5]);
      acc[6] = fmaf(xv, wb.z, acc[6]);   acc[7] = fmaf(xv, wb.w, acc[7]);
      acc[8] = fmaf(xv, wc.x, acc[8]);   acc[9] = fmaf(xv, wc.y, acc[9]);
      acc[10] = fmaf(xv, wc.z, acc[10]); acc[11] = fmaf(xv, wc.w, acc[11]);
      acc[12] = fmaf(xv, wd.x, acc[12]); acc[13] = fmaf(xv, wd.y, acc[13]);
      acc[14] = fmaf(xv, wd.z, acc[14]); acc[15] = fmaf(xv, wd.w, acc[15]);
    }
  }

  if (row < N_NODES) {
    float dv = dinv[row];
#pragma unroll
    for (int c = 0; c < FH; c++) acc[c] *= dv;
#pragma unroll
    for (int q = 0; q < 4; q++)
      *(float4*)(p1 + (size_t)row * FH + q * 4) = ((const float4*)acc)[q];
  }
}

// ---- gather layer 1: q = dinv * relu(dinv * (p1[self] + sum p1[src]) + b1) ----
// one wave per node; csr reads NT (read-once stream, keep L2 for p1 table).

__global__ __launch_bounds__(256) void k_gather1(const int* __restrict__ off,
                                                 const int* __restrict__ csr,
                                                 const float* __restrict__ p1,
                                                 const float* __restrict__ dinv,
                                                 const float* __restrict__ b1,
                                                 float* __restrict__ q) {
  int lane = threadIdx.x & 63;
  int node = blockIdx.x * 4 + (threadIdx.x >> 6);
  int start = off[node];
  int end = off[node + 1];
  int slot = lane >> 2, comp = lane & 3;
  float4 acc = make_float4(0.f, 0.f, 0.f, 0.f);
  if (slot == 0)  // self-loop
    acc = *(const float4*)(p1 + (size_t)node * FH + comp * 4);
  for (int base = start; base < end; base += 32) {
    int e0 = base + slot, e1 = e0 + 16;
    int s0 = (e0 < end) ? __builtin_nontemporal_load(csr + e0) : -1;
    int s1 = (e1 < end) ? __builtin_nontemporal_load(csr + e1) : -1;
    if (s0 >= 0) {
      float4 v = *(const float4*)(p1 + (size_t)s0 * FH + comp * 4);
      acc.x += v.x; acc.y += v.y; acc.z += v.z; acc.w += v.w;
    }
    if (s1 >= 0) {
      float4 v = *(const float4*)(p1 + (size_t)s1 * FH + comp * 4);
      acc.x += v.x; acc.y += v.y; acc.z += v.z; acc.w += v.w;
    }
  }
#pragma unroll
  for (int m = 4; m <= 32; m <<= 1) {
    acc.x += __shfl_xor(acc.x, m);
    acc.y += __shfl_xor(acc.y, m);
    acc.z += __shfl_xor(acc.z, m);
    acc.w += __shfl_xor(acc.w, m);
  }
  float dv = dinv[node];
  if (lane < 4) {  // comp == lane
    float4 bb = *(const float4*)(b1 + lane * 4);
    float4 r;
    r.x = fmaxf(fmaf(acc.x, dv, bb.x), 0.f) * dv;
    r.y = fmaxf(fmaf(acc.y, dv, bb.y), 0.f) * dv;
    r.z = fmaxf(fmaf(acc.z, dv, bb.z), 0.f) * dv;
    r.w = fmaxf(fmaf(acc.w, dv, bb.w), 0.f) * dv;
    *(float4*)(q + (size_t)node * FH + lane * 4) = r;
  }
}

// ---- gather layer 2 + W2 matvec + log_softmax, fused ----

__global__ __launch_bounds__(256) void k_gather2(const int* __restrict__ off,
                                                 const int* __restrict__ csr,
                                                 const float* __restrict__ q,
                                                 const float* __restrict__ dinv,
                                                 const float* __restrict__ W2,
                                                 const float* __restrict__ b2,
                                                 float* __restrict__ out) {
  int lane = threadIdx.x & 63;
  int node = blockIdx.x * 4 + (threadIdx.x >> 6);
  int start = off[node];
  int end = off[node + 1];
  int slot = lane >> 2, comp = lane & 3;
  float4 acc = make_float4(0.f, 0.f, 0.f, 0.f);
  if (slot == 0)  // self-loop
    acc = *(const float4*)(q + (size_t)node * FH + comp * 4);
  for (int base = start; base < end; base += 32) {
    int e0 = base + slot, e1 = e0 + 16;
    int s0 = (e0 < end) ? __builtin_nontemporal_load(csr + e0) : -1;
    int s1 = (e1 < end) ? __builtin_nontemporal_load(csr + e1) : -1;
    if (s0 >= 0) {
      float4 v = *(const float4*)(q + (size_t)s0 * FH + comp * 4);
      acc.x += v.x; acc.y += v.y; acc.z += v.z; acc.w += v.w;
    }
    if (s1 >= 0) {
      float4 v = *(const float4*)(q + (size_t)s1 * FH + comp * 4);
      acc.x += v.x; acc.y += v.y; acc.z += v.z; acc.w += v.w;
    }
  }
#pragma unroll
  for (int m = 4; m <= 32; m <<= 1) {
    acc.x += __shfl_xor(acc.x, m);
    acc.y += __shfl_xor(acc.y, m);
    acc.z += __shfl_xor(acc.z, m);
    acc.w += __shfl_xor(acc.w, m);
  }
  float dv = dinv[node];
  acc.x *= dv; acc.y *= dv; acc.z *= dv; acc.w *= dv;
  float t16[16];
  t16[comp * 4 + 0] = acc.x; t16[comp * 4 + 1] = acc.y;
  t16[comp * 4 + 2] = acc.z; t16[comp * 4 + 3] = acc.w;
#pragma unroll
  for (int m = 1; m <= 3; m++) {
    int oc = comp ^ m;
    t16[oc * 4 + 0] = __shfl_xor(acc.x, m);
    t16[oc * 4 + 1] = __shfl_xor(acc.y, m);
    t16[oc * 4 + 2] = __shfl_xor(acc.z, m);
    t16[oc * 4 + 3] = __shfl_xor(acc.w, m);
  }
  float z = -1e30f;
  if (lane < FC) {
    z = b2[lane];
#pragma unroll
    for (int k = 0; k < FH; k++) z = fmaf(t16[k], W2[k * FC + lane], z);
  }
  float mx = z;
#pragma unroll
  for (int d = 1; d < 64; d <<= 1) mx = fmaxf(mx, __shfl_xor(mx, d));
  float ex = (lane < FC) ? __expf(z - mx) : 0.f;
#pragma unroll
  for (int d = 1; d < 64; d <<= 1) ex += __shfl_xor(ex, d);
  float l = __logf(ex) + mx;
  if (lane < FC) out[(size_t)node * FC + lane] = z - l;
}

// ---------------- launch ----------------

extern "C" void kernel_launch(void* const* d_in, const int* in_sizes, int n_in,
                              void* d_out, int out_size, void* d_ws, size_t ws_size,
                              hipStream_t stream) {
  const float* x  = (const float*)d_in[0];
  const int*   ei = (const int*)d_in[1];  // [2, E] int32
  const float* W1 = (const float*)d_in[2];
  const float* b1 = (const float*)d_in[3];
  const float* W2 = (const float*)d_in[4];
  const float* b2 = (const float*)d_in[5];
  float* out = (float*)d_out;

  // workspace (ints): H | P | T | Base | off | csr | stage(->p1|q) | dinv
  int* wsi  = (int*)d_ws;
  int* H    = wsi;                  // 100096
  int* P    = H + 100096;           // 100096
  int* T    = P + 100096;           // 512
  int* Base = T + 512;              // 512
  int* off  = Base + 512;           // 100352
  int* csr  = off + 100352;         // 3200000
  int* stage = csr + 3200000;       // 3200000
  float* dinv = (float*)(stage + 3200000);  // 100352
  float* p1 = (float*)stage;        // stage dead after kB
  float* q  = p1 + 1600000;

  kA1 <<<NBLK_P, 256, 0, stream>>>(ei + N_EDGES, H);
  kA2 <<<NBKT,   256, 0, stream>>>(H, P, T);
  kA3s<<<1,      512, 0, stream>>>(T, Base, off);
  kA3 <<<NBLK_P, 256, 0, stream>>>(ei, Base, P, stage);
  kB  <<<NBKT,   256, 0, stream>>>(stage, Base, T, off, csr, dinv);
  k_gemm1  <<<NB_N, 256, 0, stream>>>(x, W1, dinv, p1);
  k_gather1<<<N_NODES / 4, 256, 0, stream>>>(off, csr, p1, dinv, b1, q);
  k_gather2<<<N_NODES / 4, 256, 0, stream>>>(off, csr, q, dinv, W2, b2, out);
}

// Round 15
// 562.291 us; speedup vs baseline: 1.5839x; 1.0041x over previous
//
#include <hip/hip_runtime.h>

#define N_NODES 100000
#define N_EDGES 3200000
#define FIN 512
#define FH 16
#define FC 40
#define NB_N ((N_NODES + 255) / 256)   // 391
#define NBKT 391                        // dst buckets: dst>>8, 256 nodes each
#define NBLK_P 256                      // partition blocks
#define CHUNK (N_EDGES / NBLK_P)        // 12500 exactly

// Lessons ledger:
// R12: NT loads on read-once streams safe; NT stores on scattered 4B = 16x
//      write amplification. R13: random cross-XCD scatter costs ~1 line
//      writeback per 4B store regardless of cache hints -> bucket-group.
// R12/R14: 3.2M device-scope atomicAdds ~ 300+ us (cross-XCD serialization)
//      -> LDS-histogram partition design is load-bearing.
// R15: p1/q packed fp16 -> 3.2MB tables fit per-XCD L2 (4MB); f32 accum.
typedef int ivec4 __attribute__((ext_vector_type(4)));
typedef _Float16 h4 __attribute__((ext_vector_type(4)));
typedef _Float16 h8 __attribute__((ext_vector_type(8)));

// ---- kA1: per-block bucket histogram (no global atomics) ----

__global__ __launch_bounds__(256) void kA1(const int* __restrict__ dst,
                                           int* __restrict__ H) {
  __shared__ int h[NBKT];
  int t = threadIdx.x;
  for (int i = t; i < NBKT; i += 256) h[i] = 0;
  __syncthreads();
  const ivec4* d4 = (const ivec4*)(dst + blockIdx.x * CHUNK);
  for (int i = t; i < CHUNK / 4; i += 256) {
    ivec4 v = __builtin_nontemporal_load(d4 + i);  // read-once stream
    atomicAdd(&h[v.x >> 8], 1);
    atomicAdd(&h[v.y >> 8], 1);
    atomicAdd(&h[v.z >> 8], 1);
    atomicAdd(&h[v.w >> 8], 1);
  }
  __syncthreads();
  for (int i = t; i < NBKT; i += 256) H[blockIdx.x * NBKT + i] = h[i];
}

// ---- kA2: per-bucket column exclusive scan over blocks; totals T ----

__global__ __launch_bounds__(256) void kA2(const int* __restrict__ H,
                                           int* __restrict__ P,
                                           int* __restrict__ T) {
  __shared__ int s[256];
  int t = threadIdx.x, b = blockIdx.x;
  int v = H[t * NBKT + b];
  s[t] = v;
  __syncthreads();
  for (int d = 1; d < 256; d <<= 1) {
    int x = (t >= d) ? s[t - d] : 0;
    __syncthreads();
    s[t] += x;
    __syncthreads();
  }
  P[t * NBKT + b] = s[t] - v;  // exclusive sum of blocks < t for bucket b
  if (t == 255) T[b] = s[t];
}

// ---- kA3s: exclusive scan of bucket totals -> Base ----

__global__ __launch_bounds__(512) void kA3s(const int* __restrict__ T,
                                            int* __restrict__ Base,
                                            int* __restrict__ off) {
  __shared__ int s[512];
  int t = threadIdx.x;
  int v = (t < NBKT) ? T[t] : 0;
  s[t] = v;
  __syncthreads();
  for (int d = 1; d < 512; d <<= 1) {
    int x = (t >= d) ? s[t - d] : 0;
    __syncthreads();
    s[t] += x;
    __syncthreads();
  }
  if (t < NBKT) Base[t] = s[t] - v;
  if (t == 0) off[N_NODES] = N_EDGES;
}

// ---- kA3: place edges into bucket-grouped staging (LDS cursors) ----

__global__ __launch_bounds__(256) void kA3(const int* __restrict__ ei,
                                           const int* __restrict__ Base,
                                           const int* __restrict__ P,
                                           int* __restrict__ stage) {
  __shared__ int cur[NBKT];
  int t = threadIdx.x, blk = blockIdx.x;
  for (int i = t; i < NBKT; i += 256) cur[i] = Base[i] + P[blk * NBKT + i];
  __syncthreads();
  int base = blk * CHUNK;
  const ivec4* s4 = (const ivec4*)(ei + base);
  const ivec4* d4 = (const ivec4*)(ei + N_EDGES + base);
  for (int i = t; i < CHUNK / 4; i += 256) {
    ivec4 sv = __builtin_nontemporal_load(s4 + i);
    ivec4 dv = __builtin_nontemporal_load(d4 + i);
    int slot;
    slot = atomicAdd(&cur[dv.x >> 8], 1); stage[slot] = sv.x | ((dv.x & 255) << 17);
    slot = atomicAdd(&cur[dv.y >> 8], 1); stage[slot] = sv.y | ((dv.y & 255) << 17);
    slot = atomicAdd(&cur[dv.z >> 8], 1); stage[slot] = sv.z | ((dv.z & 255) << 17);
    slot = atomicAdd(&cur[dv.w >> 8], 1); stage[slot] = sv.w | ((dv.w & 255) << 17);
  }
}

// ---- kB: per-bucket CSR finalize: off[], dinv[], csr[] (all block-local) ----

__global__ __launch_bounds__(256) void kB(const int* __restrict__ stage,
                                          const int* __restrict__ Base,
                                          const int* __restrict__ T,
                                          int* __restrict__ off,
                                          int* __restrict__ csr,
                                          float* __restrict__ dinv) {
  __shared__ int hist[256], cursor[256], sc[256];
  int t = threadIdx.x, b = blockIdx.x;
  int base = Base[b], cnt = T[b];
  hist[t] = 0;
  __syncthreads();
  for (int i = t; i < cnt; i += 256) atomicAdd(&hist[stage[base + i] >> 17], 1);
  __syncthreads();
  int c = hist[t];
  sc[t] = c;
  __syncthreads();
  for (int d = 1; d < 256; d <<= 1) {
    int x = (t >= d) ? sc[t - d] : 0;
    __syncthreads();
    sc[t] += x;
    __syncthreads();
  }
  int excl = sc[t] - c;
  int node = b * 256 + t;
  if (node < N_NODES) {
    off[node] = base + excl;
    dinv[node] = rsqrtf((float)(c + 1));  // +1 self-loop
  }
  cursor[t] = excl;
  __syncthreads();
  for (int i = t; i < cnt; i += 256) {
    int pk = stage[base + i];
    int slot = atomicAdd(&cursor[pk >> 17], 1);  // LDS atomic
    csr[base + slot] = pk & 0x1FFFF;
  }
}

// ---------------- layer 1 GEMM: p1 = fp16(dinv * (x @ W1)) ----------------

__global__ __launch_bounds__(256) void k_gemm1(const float* __restrict__ x,
                                               const float* __restrict__ W1,
                                               const float* __restrict__ dinv,
                                               _Float16* __restrict__ p1) {
  __shared__ float xs[256 * 36];
  const int t = threadIdx.x;
  const int row0 = blockIdx.x * 256;
  const int row = row0 + t;
  float acc[FH];
#pragma unroll
  for (int c = 0; c < FH; c++) acc[c] = 0.0f;

  for (int kc = 0; kc < FIN; kc += 32) {
    float4 ld[8];
#pragma unroll
    for (int i = 0; i < 8; i++) {
      int idx = t + 256 * i;
      int r = idx >> 3, c4 = idx & 7;
      int gr = row0 + r;
      ld[i] = (gr < N_NODES)
                  ? *(const float4*)(x + (size_t)gr * FIN + kc + c4 * 4)
                  : make_float4(0.f, 0.f, 0.f, 0.f);
    }
    __syncthreads();
#pragma unroll
    for (int i = 0; i < 8; i++) {
      int idx = t + 256 * i;
      int r = idx >> 3, c4 = idx & 7;
      *(float4*)(&xs[r * 36 + c4 * 4]) = ld[i];
    }
    __syncthreads();
    float4 xr[8];
#pragma unroll
    for (int q = 0; q < 8; q++) xr[q] = *(const float4*)(&xs[t * 36 + q * 4]);
    const float4* w4 = (const float4*)(W1 + (size_t)kc * FH);  // wave-uniform
#pragma unroll
    for (int k = 0; k < 32; k++) {
      float xv = ((const float*)xr)[k];
      float4 wa = w4[k * 4 + 0], wb = w4[k * 4 + 1];
      float4 wc = w4[k * 4 + 2], wd = w4[k * 4 + 3];
      acc[0] = fmaf(xv, wa.x, acc[0]);   acc[1] = fmaf(xv, wa.y, acc[1]);
      acc[2] = fmaf(xv, wa.z, acc[2]);   acc[3] = fmaf(xv, wa.w, acc[3]);
      acc[4] = fmaf(xv, wb.x, acc[4]);   acc[5] = fmaf(xv, wb.y, acc[5]);
      acc[6] = fmaf(xv, wb.z, acc[6]);   acc[7] = fmaf(xv, wb.w, acc[7]);
      acc[8] = fmaf(xv, wc.x, acc[8]);   acc[9] = fmaf(xv, wc.y, acc[9]);
      acc[10] = fmaf(xv, wc.z, acc[10]); acc[11] = fmaf(xv, wc.w, acc[11]);
      acc[12] = fmaf(xv, wd.x, acc[12]); acc[13] = fmaf(xv, wd.y, acc[13]);
      acc[14] = fmaf(xv, wd.z, acc[14]); acc[15] = fmaf(xv, wd.w, acc[15]);
    }
  }

  if (row < N_NODES) {
    float dv = dinv[row];
    h8 o0, o1;
#pragma unroll
    for (int c = 0; c < 8; c++) {
      o0[c] = (_Float16)(acc[c] * dv);
      o1[c] = (_Float16)(acc[8 + c] * dv);
    }
    *(h8*)(p1 + (size_t)row * FH) = o0;
    *(h8*)(p1 + (size_t)row * FH + 8) = o1;
  }
}

// ---- gather layer 1: q = fp16(dinv * relu(dinv * (p1[self]+sum p1[src]) + b1)) ----
// fp16 table is 3.2MB -> per-XCD-L2-resident; f32 accumulate.

__global__ __launch_bounds__(256) void k_gather1(const int* __restrict__ off,
                                                 const int* __restrict__ csr,
                                                 const _Float16* __restrict__ p1,
                                                 const float* __restrict__ dinv,
                                                 const float* __restrict__ b1,
                                                 _Float16* __restrict__ q) {
  int lane = threadIdx.x & 63;
  int node = blockIdx.x * 4 + (threadIdx.x >> 6);
  int start = off[node];
  int end = off[node + 1];
  int slot = lane >> 2, comp = lane & 3;
  float4 acc = make_float4(0.f, 0.f, 0.f, 0.f);
  if (slot == 0) {  // self-loop
    h4 v = *(const h4*)(p1 + (size_t)node * FH + comp * 4);
    acc.x = (float)v[0]; acc.y = (float)v[1];
    acc.z = (float)v[2]; acc.w = (float)v[3];
  }
  for (int base = start; base < end; base += 32) {
    int e0 = base + slot, e1 = e0 + 16;
    int s0 = (e0 < end) ? __builtin_nontemporal_load(csr + e0) : -1;
    int s1 = (e1 < end) ? __builtin_nontemporal_load(csr + e1) : -1;
    if (s0 >= 0) {
      h4 v = *(const h4*)(p1 + (size_t)s0 * FH + comp * 4);
      acc.x += (float)v[0]; acc.y += (float)v[1];
      acc.z += (float)v[2]; acc.w += (float)v[3];
    }
    if (s1 >= 0) {
      h4 v = *(const h4*)(p1 + (size_t)s1 * FH + comp * 4);
      acc.x += (float)v[0]; acc.y += (float)v[1];
      acc.z += (float)v[2]; acc.w += (float)v[3];
    }
  }
#pragma unroll
  for (int m = 4; m <= 32; m <<= 1) {
    acc.x += __shfl_xor(acc.x, m);
    acc.y += __shfl_xor(acc.y, m);
    acc.z += __shfl_xor(acc.z, m);
    acc.w += __shfl_xor(acc.w, m);
  }
  float dv = dinv[node];
  if (lane < 4) {  // comp == lane
    float4 bb = *(const float4*)(b1 + lane * 4);
    h4 o;
    o[0] = (_Float16)(fmaxf(fmaf(acc.x, dv, bb.x), 0.f) * dv);
    o[1] = (_Float16)(fmaxf(fmaf(acc.y, dv, bb.y), 0.f) * dv);
    o[2] = (_Float16)(fmaxf(fmaf(acc.z, dv, bb.z), 0.f) * dv);
    o[3] = (_Float16)(fmaxf(fmaf(acc.w, dv, bb.w), 0.f) * dv);
    *(h4*)(q + (size_t)node * FH + lane * 4) = o;
  }
}

// ---- gather layer 2 + W2 matvec + log_softmax, fused ----

__global__ __launch_bounds__(256) void k_gather2(const int* __restrict__ off,
                                                 const int* __restrict__ csr,
                                                 const _Float16* __restrict__ q,
                                                 const float* __restrict__ dinv,
                                                 const float* __restrict__ W2,
                                                 const float* __restrict__ b2,
                                                 float* __restrict__ out) {
  int lane = threadIdx.x & 63;
  int node = blockIdx.x * 4 + (threadIdx.x >> 6);
  int start = off[node];
  int end = off[node + 1];
  int slot = lane >> 2, comp = lane & 3;
  float4 acc = make_float4(0.f, 0.f, 0.f, 0.f);
  if (slot == 0) {  // self-loop
    h4 v = *(const h4*)(q + (size_t)node * FH + comp * 4);
    acc.x = (float)v[0]; acc.y = (float)v[1];
    acc.z = (float)v[2]; acc.w = (float)v[3];
  }
  for (int base = start; base < end; base += 32) {
    int e0 = base + slot, e1 = e0 + 16;
    int s0 = (e0 < end) ? __builtin_nontemporal_load(csr + e0) : -1;
    int s1 = (e1 < end) ? __builtin_nontemporal_load(csr + e1) : -1;
    if (s0 >= 0) {
      h4 v = *(const h4*)(q + (size_t)s0 * FH + comp * 4);
      acc.x += (float)v[0]; acc.y += (float)v[1];
      acc.z += (float)v[2]; acc.w += (float)v[3];
    }
    if (s1 >= 0) {
      h4 v = *(const h4*)(q + (size_t)s1 * FH + comp * 4);
      acc.x += (float)v[0]; acc.y += (float)v[1];
      acc.z += (float)v[2]; acc.w += (float)v[3];
    }
  }
#pragma unroll
  for (int m = 4; m <= 32; m <<= 1) {
    acc.x += __shfl_xor(acc.x, m);
    acc.y += __shfl_xor(acc.y, m);
    acc.z += __shfl_xor(acc.z, m);
    acc.w += __shfl_xor(acc.w, m);
  }
  float dv = dinv[node];
  acc.x *= dv; acc.y *= dv; acc.z *= dv; acc.w *= dv;
  float t16[16];
  t16[comp * 4 + 0] = acc.x; t16[comp * 4 + 1] = acc.y;
  t16[comp * 4 + 2] = acc.z; t16[comp * 4 + 3] = acc.w;
#pragma unroll
  for (int m = 1; m <= 3; m++) {
    int oc = comp ^ m;
    t16[oc * 4 + 0] = __shfl_xor(acc.x, m);
    t16[oc * 4 + 1] = __shfl_xor(acc.y, m);
    t16[oc * 4 + 2] = __shfl_xor(acc.z, m);
    t16[oc * 4 + 3] = __shfl_xor(acc.w, m);
  }
  float z = -1e30f;
  if (lane < FC) {
    z = b2[lane];
#pragma unroll
    for (int k = 0; k < FH; k++) z = fmaf(t16[k], W2[k * FC + lane], z);
  }
  float mx = z;
#pragma unroll
  for (int d = 1; d < 64; d <<= 1) mx = fmaxf(mx, __shfl_xor(mx, d));
  float ex = (lane < FC) ? __expf(z - mx) : 0.f;
#pragma unroll
  for (int d = 1; d < 64; d <<= 1) ex += __shfl_xor(ex, d);
  float l = __logf(ex) + mx;
  if (lane < FC) out[(size_t)node * FC + lane] = z - l;
}

// ---------------- launch ----------------

extern "C" void kernel_launch(void* const* d_in, const int* in_sizes, int n_in,
                              void* d_out, int out_size, void* d_ws, size_t ws_size,
                              hipStream_t stream) {
  const float* x  = (const float*)d_in[0];
  const int*   ei = (const int*)d_in[1];  // [2, E] int32
  const float* W1 = (const float*)d_in[2];
  const float* b1 = (const float*)d_in[3];
  const float* W2 = (const float*)d_in[4];
  const float* b2 = (const float*)d_in[5];
  float* out = (float*)d_out;

  // workspace (ints): H | P | T | Base | off | csr | stage(->p1|q fp16) | dinv
  int* wsi  = (int*)d_ws;
  int* H    = wsi;                  // 100096
  int* P    = H + 100096;           // 100096
  int* T    = P + 100096;           // 512
  int* Base = T + 512;              // 512
  int* off  = Base + 512;           // 100352
  int* csr  = off + 100352;         // 3200000
  int* stage = csr + 3200000;       // 3200000
  float* dinv = (float*)(stage + 3200000);  // 100352
  _Float16* p1 = (_Float16*)stage;  // stage dead after kB; 1.6M halves
  _Float16* q  = p1 + 1600000;      // 1.6M halves

  kA1 <<<NBLK_P, 256, 0, stream>>>(ei + N_EDGES, H);
  kA2 <<<NBKT,   256, 0, stream>>>(H, P, T);
  kA3s<<<1,      512, 0, stream>>>(T, Base, off);
  kA3 <<<NBLK_P, 256, 0, stream>>>(ei, Base, P, stage);
  kB  <<<NBKT,   256, 0, stream>>>(stage, Base, T, off, csr, dinv);
  k_gemm1  <<<NB_N, 256, 0, stream>>>(x, W1, dinv, p1);
  k_gather1<<<N_NODES / 4, 256, 0, stream>>>(off, csr, p1, dinv, b1, q);
  k_gather2<<<N_NODES / 4, 256, 0, stream>>>(off, csr, q, dinv, W2, b2, out);
}

// Round 16
// 554.016 us; speedup vs baseline: 1.6075x; 1.0149x over previous
//
#include <hip/hip_runtime.h>

#define N_NODES 100000
#define N_EDGES 3200000
#define FIN 512
#define FH 16
#define FC 40
#define NB_N ((N_NODES + 255) / 256)   // 391
#define NBKT 391                        // dst buckets: dst>>8, 256 nodes each
#define NBLK_P 256                      // partition blocks
#define CHUNK (N_EDGES / NBLK_P)        // 12500 exactly

// Lessons ledger:
// R12: NT loads on read-once streams safe; NT stores on scattered 4B = 16x
//      write amplification. R13: random cross-XCD scatter costs ~1 line
//      writeback per 4B store regardless of cache hints -> bucket-group.
// R12/R14: 3.2M device-scope atomicAdds ~ 300+ us -> LDS-histogram design.
// R15: fp16 p1/q tables: time-neutral (gathers not table-BW-bound), absmax
//      unchanged -> keep. k_gemm1 = 120.7us @ 11% HBM, 11% VALU, 17% occ ->
//      latency-bound (1.5 blocks/CU, serialized phases). No NT on x (L3
//      keeps 100MB of it warm across iterations).
// R16: double-buffer gemm1 staging -> hide HBM latency under FMA phase.
typedef int ivec4 __attribute__((ext_vector_type(4)));
typedef _Float16 h4 __attribute__((ext_vector_type(4)));
typedef _Float16 h8 __attribute__((ext_vector_type(8)));

// ---- kA1: per-block bucket histogram (no global atomics) ----

__global__ __launch_bounds__(256) void kA1(const int* __restrict__ dst,
                                           int* __restrict__ H) {
  __shared__ int h[NBKT];
  int t = threadIdx.x;
  for (int i = t; i < NBKT; i += 256) h[i] = 0;
  __syncthreads();
  const ivec4* d4 = (const ivec4*)(dst + blockIdx.x * CHUNK);
  for (int i = t; i < CHUNK / 4; i += 256) {
    ivec4 v = __builtin_nontemporal_load(d4 + i);  // read-once stream
    atomicAdd(&h[v.x >> 8], 1);
    atomicAdd(&h[v.y >> 8], 1);
    atomicAdd(&h[v.z >> 8], 1);
    atomicAdd(&h[v.w >> 8], 1);
  }
  __syncthreads();
  for (int i = t; i < NBKT; i += 256) H[blockIdx.x * NBKT + i] = h[i];
}

// ---- kA2: per-bucket column exclusive scan over blocks; totals T ----

__global__ __launch_bounds__(256) void kA2(const int* __restrict__ H,
                                           int* __restrict__ P,
                                           int* __restrict__ T) {
  __shared__ int s[256];
  int t = threadIdx.x, b = blockIdx.x;
  int v = H[t * NBKT + b];
  s[t] = v;
  __syncthreads();
  for (int d = 1; d < 256; d <<= 1) {
    int x = (t >= d) ? s[t - d] : 0;
    __syncthreads();
    s[t] += x;
    __syncthreads();
  }
  P[t * NBKT + b] = s[t] - v;  // exclusive sum of blocks < t for bucket b
  if (t == 255) T[b] = s[t];
}

// ---- kA3s: exclusive scan of bucket totals -> Base ----

__global__ __launch_bounds__(512) void kA3s(const int* __restrict__ T,
                                            int* __restrict__ Base,
                                            int* __restrict__ off) {
  __shared__ int s[512];
  int t = threadIdx.x;
  int v = (t < NBKT) ? T[t] : 0;
  s[t] = v;
  __syncthreads();
  for (int d = 1; d < 512; d <<= 1) {
    int x = (t >= d) ? s[t - d] : 0;
    __syncthreads();
    s[t] += x;
    __syncthreads();
  }
  if (t < NBKT) Base[t] = s[t] - v;
  if (t == 0) off[N_NODES] = N_EDGES;
}

// ---- kA3: place edges into bucket-grouped staging (LDS cursors) ----

__global__ __launch_bounds__(256) void kA3(const int* __restrict__ ei,
                                           const int* __restrict__ Base,
                                           const int* __restrict__ P,
                                           int* __restrict__ stage) {
  __shared__ int cur[NBKT];
  int t = threadIdx.x, blk = blockIdx.x;
  for (int i = t; i < NBKT; i += 256) cur[i] = Base[i] + P[blk * NBKT + i];
  __syncthreads();
  int base = blk * CHUNK;
  const ivec4* s4 = (const ivec4*)(ei + base);
  const ivec4* d4 = (const ivec4*)(ei + N_EDGES + base);
  for (int i = t; i < CHUNK / 4; i += 256) {
    ivec4 sv = __builtin_nontemporal_load(s4 + i);
    ivec4 dv = __builtin_nontemporal_load(d4 + i);
    int slot;
    slot = atomicAdd(&cur[dv.x >> 8], 1); stage[slot] = sv.x | ((dv.x & 255) << 17);
    slot = atomicAdd(&cur[dv.y >> 8], 1); stage[slot] = sv.y | ((dv.y & 255) << 17);
    slot = atomicAdd(&cur[dv.z >> 8], 1); stage[slot] = sv.z | ((dv.z & 255) << 17);
    slot = atomicAdd(&cur[dv.w >> 8], 1); stage[slot] = sv.w | ((dv.w & 255) << 17);
  }
}

// ---- kB: per-bucket CSR finalize: off[], dinv[], csr[] (all block-local) ----

__global__ __launch_bounds__(256) void kB(const int* __restrict__ stage,
                                          const int* __restrict__ Base,
                                          const int* __restrict__ T,
                                          int* __restrict__ off,
                                          int* __restrict__ csr,
                                          float* __restrict__ dinv) {
  __shared__ int hist[256], cursor[256], sc[256];
  int t = threadIdx.x, b = blockIdx.x;
  int base = Base[b], cnt = T[b];
  hist[t] = 0;
  __syncthreads();
  for (int i = t; i < cnt; i += 256) atomicAdd(&hist[stage[base + i] >> 17], 1);
  __syncthreads();
  int c = hist[t];
  sc[t] = c;
  __syncthreads();
  for (int d = 1; d < 256; d <<= 1) {
    int x = (t >= d) ? sc[t - d] : 0;
    __syncthreads();
    sc[t] += x;
    __syncthreads();
  }
  int excl = sc[t] - c;
  int node = b * 256 + t;
  if (node < N_NODES) {
    off[node] = base + excl;
    dinv[node] = rsqrtf((float)(c + 1));  // +1 self-loop
  }
  cursor[t] = excl;
  __syncthreads();
  for (int i = t; i < cnt; i += 256) {
    int pk = stage[base + i];
    int slot = atomicAdd(&cursor[pk >> 17], 1);  // LDS atomic
    csr[base + slot] = pk & 0x1FFFF;
  }
}

// ---------------- layer 1 GEMM: p1 = fp16(dinv * (x @ W1)) ----------------
// Double-buffered: chunk k+1's global loads issue before chunk k's FMA loop,
// hiding ~900cy HBM latency under the ~1024cy compute phase (R15: 120.7us at
// 11% HBM / 11% VALU / 17% occ = latency-bound serialized phases).

__global__ __launch_bounds__(256) void k_gemm1(const float* __restrict__ x,
                                               const float* __restrict__ W1,
                                               const float* __restrict__ dinv,
                                               _Float16* __restrict__ p1) {
  __shared__ float xs[256 * 36];
  const int t = threadIdx.x;
  const int row0 = blockIdx.x * 256;
  const int row = row0 + t;
  float acc[FH];
#pragma unroll
  for (int c = 0; c < FH; c++) acc[c] = 0.0f;

  float4 ld[8];
#pragma unroll
  for (int i = 0; i < 8; i++) {  // prologue: load chunk kc=0
    int idx = t + 256 * i;
    int r = idx >> 3, c4 = idx & 7;
    int gr = row0 + r;
    ld[i] = (gr < N_NODES)
                ? *(const float4*)(x + (size_t)gr * FIN + 0 + c4 * 4)
                : make_float4(0.f, 0.f, 0.f, 0.f);
  }

  for (int kc = 0; kc < FIN; kc += 32) {
    __syncthreads();  // xs free (all waves done reading previous chunk)
#pragma unroll
    for (int i = 0; i < 8; i++) {
      int idx = t + 256 * i;
      int r = idx >> 3, c4 = idx & 7;
      *(float4*)(&xs[r * 36 + c4 * 4]) = ld[i];
    }
    __syncthreads();  // xs ready
    if (kc + 32 < FIN) {
#pragma unroll
      for (int i = 0; i < 8; i++) {  // issue next-chunk loads; land under FMAs
        int idx = t + 256 * i;
        int r = idx >> 3, c4 = idx & 7;
        int gr = row0 + r;
        ld[i] = (gr < N_NODES)
                    ? *(const float4*)(x + (size_t)gr * FIN + (kc + 32) + c4 * 4)
                    : make_float4(0.f, 0.f, 0.f, 0.f);
      }
    }
    float4 xr[8];
#pragma unroll
    for (int q = 0; q < 8; q++) xr[q] = *(const float4*)(&xs[t * 36 + q * 4]);
    const float4* w4 = (const float4*)(W1 + (size_t)kc * FH);  // wave-uniform
#pragma unroll
    for (int k = 0; k < 32; k++) {
      float xv = ((const float*)xr)[k];
      float4 wa = w4[k * 4 + 0], wb = w4[k * 4 + 1];
      float4 wc = w4[k * 4 + 2], wd = w4[k * 4 + 3];
      acc[0] = fmaf(xv, wa.x, acc[0]);   acc[1] = fmaf(xv, wa.y, acc[1]);
      acc[2] = fmaf(xv, wa.z, acc[2]);   acc[3] = fmaf(xv, wa.w, acc[3]);
      acc[4] = fmaf(xv, wb.x, acc[4]);   acc[5] = fmaf(xv, wb.y, acc[5]);
      acc[6] = fmaf(xv, wb.z, acc[6]);   acc[7] = fmaf(xv, wb.w, acc[7]);
      acc[8] = fmaf(xv, wc.x, acc[8]);   acc[9] = fmaf(xv, wc.y, acc[9]);
      acc[10] = fmaf(xv, wc.z, acc[10]); acc[11] = fmaf(xv, wc.w, acc[11]);
      acc[12] = fmaf(xv, wd.x, acc[12]); acc[13] = fmaf(xv, wd.y, acc[13]);
      acc[14] = fmaf(xv, wd.z, acc[14]); acc[15] = fmaf(xv, wd.w, acc[15]);
    }
  }

  if (row < N_NODES) {
    float dv = dinv[row];
    h8 o0, o1;
#pragma unroll
    for (int c = 0; c < 8; c++) {
      o0[c] = (_Float16)(acc[c] * dv);
      o1[c] = (_Float16)(acc[8 + c] * dv);
    }
    *(h8*)(p1 + (size_t)row * FH) = o0;
    *(h8*)(p1 + (size_t)row * FH + 8) = o1;
  }
}

// ---- gather layer 1: q = fp16(dinv * relu(dinv * (p1[self]+sum p1[src]) + b1)) ----

__global__ __launch_bounds__(256) void k_gather1(const int* __restrict__ off,
                                                 const int* __restrict__ csr,
                                                 const _Float16* __restrict__ p1,
                                                 const float* __restrict__ dinv,
                                                 const float* __restrict__ b1,
                                                 _Float16* __restrict__ q) {
  int lane = threadIdx.x & 63;
  int node = blockIdx.x * 4 + (threadIdx.x >> 6);
  int start = off[node];
  int end = off[node + 1];
  int slot = lane >> 2, comp = lane & 3;
  float4 acc = make_float4(0.f, 0.f, 0.f, 0.f);
  if (slot == 0) {  // self-loop
    h4 v = *(const h4*)(p1 + (size_t)node * FH + comp * 4);
    acc.x = (float)v[0]; acc.y = (float)v[1];
    acc.z = (float)v[2]; acc.w = (float)v[3];
  }
  for (int base = start; base < end; base += 32) {
    int e0 = base + slot, e1 = e0 + 16;
    int s0 = (e0 < end) ? __builtin_nontemporal_load(csr + e0) : -1;
    int s1 = (e1 < end) ? __builtin_nontemporal_load(csr + e1) : -1;
    if (s0 >= 0) {
      h4 v = *(const h4*)(p1 + (size_t)s0 * FH + comp * 4);
      acc.x += (float)v[0]; acc.y += (float)v[1];
      acc.z += (float)v[2]; acc.w += (float)v[3];
    }
    if (s1 >= 0) {
      h4 v = *(const h4*)(p1 + (size_t)s1 * FH + comp * 4);
      acc.x += (float)v[0]; acc.y += (float)v[1];
      acc.z += (float)v[2]; acc.w += (float)v[3];
    }
  }
#pragma unroll
  for (int m = 4; m <= 32; m <<= 1) {
    acc.x += __shfl_xor(acc.x, m);
    acc.y += __shfl_xor(acc.y, m);
    acc.z += __shfl_xor(acc.z, m);
    acc.w += __shfl_xor(acc.w, m);
  }
  float dv = dinv[node];
  if (lane < 4) {  // comp == lane
    float4 bb = *(const float4*)(b1 + lane * 4);
    h4 o;
    o[0] = (_Float16)(fmaxf(fmaf(acc.x, dv, bb.x), 0.f) * dv);
    o[1] = (_Float16)(fmaxf(fmaf(acc.y, dv, bb.y), 0.f) * dv);
    o[2] = (_Float16)(fmaxf(fmaf(acc.z, dv, bb.z), 0.f) * dv);
    o[3] = (_Float16)(fmaxf(fmaf(acc.w, dv, bb.w), 0.f) * dv);
    *(h4*)(q + (size_t)node * FH + lane * 4) = o;
  }
}

// ---- gather layer 2 + W2 matvec + log_softmax, fused ----

__global__ __launch_bounds__(256) void k_gather2(const int* __restrict__ off,
                                                 const int* __restrict__ csr,
                                                 const _Float16* __restrict__ q,
                                                 const float* __restrict__ dinv,
                                                 const float* __restrict__ W2,
                                                 const float* __restrict__ b2,
                                                 float* __restrict__ out) {
  int lane = threadIdx.x & 63;
  int node = blockIdx.x * 4 + (threadIdx.x >> 6);
  int start = off[node];
  int end = off[node + 1];
  int slot = lane >> 2, comp = lane & 3;
  float4 acc = make_float4(0.f, 0.f, 0.f, 0.f);
  if (slot == 0) {  // self-loop
    h4 v = *(const h4*)(q + (size_t)node * FH + comp * 4);
    acc.x = (float)v[0]; acc.y = (float)v[1];
    acc.z = (float)v[2]; acc.w = (float)v[3];
  }
  for (int base = start; base < end; base += 32) {
    int e0 = base + slot, e1 = e0 + 16;
    int s0 = (e0 < end) ? __builtin_nontemporal_load(csr + e0) : -1;
    int s1 = (e1 < end) ? __builtin_nontemporal_load(csr + e1) : -1;
    if (s0 >= 0) {
      h4 v = *(const h4*)(q + (size_t)s0 * FH + comp * 4);
      acc.x += (float)v[0]; acc.y += (float)v[1];
      acc.z += (float)v[2]; acc.w += (float)v[3];
    }
    if (s1 >= 0) {
      h4 v = *(const h4*)(q + (size_t)s1 * FH + comp * 4);
      acc.x += (float)v[0]; acc.y += (float)v[1];
      acc.z += (float)v[2]; acc.w += (float)v[3];
    }
  }
#pragma unroll
  for (int m = 4; m <= 32; m <<= 1) {
    acc.x += __shfl_xor(acc.x, m);
    acc.y += __shfl_xor(acc.y, m);
    acc.z += __shfl_xor(acc.z, m);
    acc.w += __shfl_xor(acc.w, m);
  }
  float dv = dinv[node];
  acc.x *= dv; acc.y *= dv; acc.z *= dv; acc.w *= dv;
  float t16[16];
  t16[comp * 4 + 0] = acc.x; t16[comp * 4 + 1] = acc.y;
  t16[comp * 4 + 2] = acc.z; t16[comp * 4 + 3] = acc.w;
#pragma unroll
  for (int m = 1; m <= 3; m++) {
    int oc = comp ^ m;
    t16[oc * 4 + 0] = __shfl_xor(acc.x, m);
    t16[oc * 4 + 1] = __shfl_xor(acc.y, m);
    t16[oc * 4 + 2] = __shfl_xor(acc.z, m);
    t16[oc * 4 + 3] = __shfl_xor(acc.w, m);
  }
  float z = -1e30f;
  if (lane < FC) {
    z = b2[lane];
#pragma unroll
    for (int k = 0; k < FH; k++) z = fmaf(t16[k], W2[k * FC + lane], z);
  }
  float mx = z;
#pragma unroll
  for (int d = 1; d < 64; d <<= 1) mx = fmaxf(mx, __shfl_xor(mx, d));
  float ex = (lane < FC) ? __expf(z - mx) : 0.f;
#pragma unroll
  for (int d = 1; d < 64; d <<= 1) ex += __shfl_xor(ex, d);
  float l = __logf(ex) + mx;
  if (lane < FC) out[(size_t)node * FC + lane] = z - l;
}

// ---------------- launch ----------------

extern "C" void kernel_launch(void* const* d_in, const int* in_sizes, int n_in,
                              void* d_out, int out_size, void* d_ws, size_t ws_size,
                              hipStream_t stream) {
  const float* x  = (const float*)d_in[0];
  const int*   ei = (const int*)d_in[1];  // [2, E] int32
  const float* W1 = (const float*)d_in[2];
  const float* b1 = (const float*)d_in[3];
  const float* W2 = (const float*)d_in[4];
  const float* b2 = (const float*)d_in[5];
  float* out = (float*)d_out;

  // workspace (ints): H | P | T | Base | off | csr | stage(->p1|q fp16) | dinv
  int* wsi  = (int*)d_ws;
  int* H    = wsi;                  // 100096
  int* P    = H + 100096;           // 100096
  int* T    = P + 100096;           // 512
  int* Base = T + 512;              // 512
  int* off  = Base + 512;           // 100352
  int* csr  = off + 100352;         // 3200000
  int* stage = csr + 3200000;       // 3200000
  float* dinv = (float*)(stage + 3200000);  // 100352
  _Float16* p1 = (_Float16*)stage;  // stage dead after kB; 1.6M halves
  _Float16* q  = p1 + 1600000;      // 1.6M halves

  kA1 <<<NBLK_P, 256, 0, stream>>>(ei + N_EDGES, H);
  kA2 <<<NBKT,   256, 0, stream>>>(H, P, T);
  kA3s<<<1,      512, 0, stream>>>(T, Base, off);
  kA3 <<<NBLK_P, 256, 0, stream>>>(ei, Base, P, stage);
  kB  <<<NBKT,   256, 0, stream>>>(stage, Base, T, off, csr, dinv);
  k_gemm1  <<<NB_N, 256, 0, stream>>>(x, W1, dinv, p1);
  k_gather1<<<N_NODES / 4, 256, 0, stream>>>(off, csr, p1, dinv, b1, q);
  k_gather2<<<N_NODES / 4, 256, 0, stream>>>(off, csr, q, dinv, W2, b2, out);
}